// Round 1
// baseline (4316.771 us; speedup 1.0000x reference)
//
#include <hip/hip_runtime.h>

// ---------------------------------------------------------------------------
// Two-layer GCN: out = Â(relu(Â(X W1) + b1) W2) + b2, Â = sym-norm adj + self loops
// Strategy: build CSR-by-dst once (deg -> scan -> fill), reuse for both layers.
// Aggregation = wave-per-node gather (lane = feature), no output atomics.
// ---------------------------------------------------------------------------

__global__ void count_deg(const int* __restrict__ dst, int e, int* __restrict__ deg) {
    int i = blockIdx.x * blockDim.x + threadIdx.x;
    if (i < e) atomicAdd(&deg[dst[i]], 1);
}

__global__ void compute_dinv(const int* __restrict__ deg, float* __restrict__ dinv, int n) {
    int i = blockIdx.x * blockDim.x + threadIdx.x;
    if (i < n) dinv[i] = rsqrtf((float)deg[i] + 1.0f);  // +1 = self loop
}

// ---- 3-phase exclusive scan over n ints (chunk = 1024 per block) ----------
__global__ void scan_a(const int* __restrict__ in, int* __restrict__ part,
                       int* __restrict__ aux, int n) {
    __shared__ int lds[256];
    int tid = threadIdx.x;
    int base = blockIdx.x * 1024 + tid * 4;
    int v0 = (base + 0 < n) ? in[base + 0] : 0;
    int v1 = (base + 1 < n) ? in[base + 1] : 0;
    int v2 = (base + 2 < n) ? in[base + 2] : 0;
    int v3 = (base + 3 < n) ? in[base + 3] : 0;
    int s = v0 + v1 + v2 + v3;
    lds[tid] = s;
    __syncthreads();
    for (int off = 1; off < 256; off <<= 1) {
        int t = (tid >= off) ? lds[tid - off] : 0;
        __syncthreads();
        lds[tid] += t;
        __syncthreads();
    }
    int excl = lds[tid] - s;
    if (base + 0 < n) part[base + 0] = excl;
    if (base + 1 < n) part[base + 1] = excl + v0;
    if (base + 2 < n) part[base + 2] = excl + v0 + v1;
    if (base + 3 < n) part[base + 3] = excl + v0 + v1 + v2;
    if (tid == 255) aux[blockIdx.x] = lds[255];
}

__global__ void scan_b(int* __restrict__ aux, int nb, int* __restrict__ total_out) {
    __shared__ int lds[256];
    int tid = threadIdx.x;
    int v = (tid < nb) ? aux[tid] : 0;
    lds[tid] = v;
    __syncthreads();
    for (int off = 1; off < 256; off <<= 1) {
        int t = (tid >= off) ? lds[tid - off] : 0;
        __syncthreads();
        lds[tid] += t;
        __syncthreads();
    }
    if (tid < nb) aux[tid] = lds[tid] - v;
    if (tid == 255) *total_out = lds[255];
}

__global__ void scan_c(const int* __restrict__ part, const int* __restrict__ aux,
                       int* __restrict__ row_off, int* __restrict__ cursor, int n) {
    int i = blockIdx.x * blockDim.x + threadIdx.x;
    if (i < n) {
        int v = part[i] + aux[i >> 10];
        row_off[i] = v;
        cursor[i] = v;
    }
}

// ---- CSR fill: slot via atomic cursor; precompute edge norm ---------------
__global__ void fill_csr(const int* __restrict__ src, const int* __restrict__ dst, int e,
                         const float* __restrict__ dinv, int* __restrict__ cursor,
                         int* __restrict__ ssrc, float* __restrict__ snorm) {
    int i = blockIdx.x * blockDim.x + threadIdx.x;
    if (i < e) {
        int s = src[i], d = dst[i];
        int p = atomicAdd(&cursor[d], 1);
        ssrc[p]  = s;
        snorm[p] = dinv[s] * dinv[d];
    }
}

// ---- GEMM H = X(K) * W(KxM), W staged fully in LDS ------------------------
// block: 256 threads = 4 waves; each thread: 4 rows x 1 col (col = lane)
template <int K, int M>
__global__ void gemm_xw(const float* __restrict__ X, const float* __restrict__ W,
                        float* __restrict__ H, int n) {
    __shared__ float w[K * M];
    int tid = threadIdx.x;
    for (int idx = tid; idx < K * M; idx += 256) w[idx] = W[idx];
    __syncthreads();
    int lane = tid & 63;
    int ty   = tid >> 6;                 // 0..3
    int r0   = blockIdx.x * 16 + ty * 4; // 16 rows per block
    float acc0 = 0.f, acc1 = 0.f, acc2 = 0.f, acc3 = 0.f;
    bool active = (lane < M);
    for (int k = 0; k < K; k += 4) {
        float4 xa = (r0 + 0 < n) ? *reinterpret_cast<const float4*>(&X[(size_t)(r0 + 0) * K + k]) : make_float4(0, 0, 0, 0);
        float4 xb = (r0 + 1 < n) ? *reinterpret_cast<const float4*>(&X[(size_t)(r0 + 1) * K + k]) : make_float4(0, 0, 0, 0);
        float4 xc = (r0 + 2 < n) ? *reinterpret_cast<const float4*>(&X[(size_t)(r0 + 2) * K + k]) : make_float4(0, 0, 0, 0);
        float4 xd = (r0 + 3 < n) ? *reinterpret_cast<const float4*>(&X[(size_t)(r0 + 3) * K + k]) : make_float4(0, 0, 0, 0);
        if (active) {
            float w0 = w[(k + 0) * M + lane];
            float w1 = w[(k + 1) * M + lane];
            float w2 = w[(k + 2) * M + lane];
            float w3 = w[(k + 3) * M + lane];
            acc0 = fmaf(xa.x, w0, acc0); acc0 = fmaf(xa.y, w1, acc0); acc0 = fmaf(xa.z, w2, acc0); acc0 = fmaf(xa.w, w3, acc0);
            acc1 = fmaf(xb.x, w0, acc1); acc1 = fmaf(xb.y, w1, acc1); acc1 = fmaf(xb.z, w2, acc1); acc1 = fmaf(xb.w, w3, acc1);
            acc2 = fmaf(xc.x, w0, acc2); acc2 = fmaf(xc.y, w1, acc2); acc2 = fmaf(xc.z, w2, acc2); acc2 = fmaf(xc.w, w3, acc2);
            acc3 = fmaf(xd.x, w0, acc3); acc3 = fmaf(xd.y, w1, acc3); acc3 = fmaf(xd.z, w2, acc3); acc3 = fmaf(xd.w, w3, acc3);
        }
    }
    if (active) {
        if (r0 + 0 < n) H[(size_t)(r0 + 0) * M + lane] = acc0;
        if (r0 + 1 < n) H[(size_t)(r0 + 1) * M + lane] = acc1;
        if (r0 + 2 < n) H[(size_t)(r0 + 2) * M + lane] = acc2;
        if (r0 + 3 < n) H[(size_t)(r0 + 3) * M + lane] = acc3;
    }
}

// ---- Aggregation: out[i] = [relu](b + dinv[i]^2 h[i] + sum_e norm_e h[src_e])
// wave per node, lane = feature
template <int M, bool RELU>
__global__ void aggregate(const float* __restrict__ H, const float* __restrict__ dinv,
                          const int* __restrict__ row_off, const int* __restrict__ ssrc,
                          const float* __restrict__ snorm, const float* __restrict__ bias,
                          float* __restrict__ out, int n) {
    int wid  = (blockIdx.x * blockDim.x + threadIdx.x) >> 6;
    int lane = threadIdx.x & 63;
    if (wid >= n) return;
    float di = dinv[wid];
    float hv = (lane < M) ? H[(size_t)wid * M + lane] : 0.f;
    float acc = di * di * hv;
    int e0 = row_off[wid], e1 = row_off[wid + 1];
    for (int e = e0; e < e1; ++e) {
        int s = ssrc[e];           // wave-uniform broadcast load
        float nm = snorm[e];
        if (lane < M) acc = fmaf(nm, H[(size_t)s * M + lane], acc);
    }
    if (lane < M) {
        float o = acc + bias[lane];
        if (RELU) o = fmaxf(o, 0.f);
        out[(size_t)wid * M + lane] = o;
    }
}

// ---------------------------------------------------------------------------
extern "C" void kernel_launch(void* const* d_in, const int* in_sizes, int n_in,
                              void* d_out, int out_size, void* d_ws, size_t ws_size,
                              hipStream_t stream) {
    const float* x  = (const float*)d_in[0];
    const int*   ei = (const int*)d_in[1];   // int32 (jax x64 disabled)
    const float* W1 = (const float*)d_in[2];
    const float* b1 = (const float*)d_in[3];
    const float* W2 = (const float*)d_in[4];
    const float* b2 = (const float*)d_in[5];

    const int gnn_f = in_sizes[3];            // 64
    const int out_f = in_sizes[5];            // 40
    const int in_f  = in_sizes[2] / gnn_f;    // 128
    const int e     = in_sizes[1] / 2;        // 1,600,000
    const int n     = in_sizes[0] / in_f;     // 100,000

    const int* src = ei;
    const int* dst = ei + e;

    // ---- workspace partition (256B aligned) ----
    char* base = (char*)d_ws;
    size_t off = 0;
    auto alloc = [&](size_t bytes) -> char* {
        char* p = base + off;
        off = (off + bytes + 255) & ~(size_t)255;
        return p;
    };
    int*   deg_cnt = (int*)  alloc((size_t)n * 4);
    float* dinv    = (float*)alloc((size_t)n * 4);
    int*   part    = (int*)  alloc((size_t)n * 4);
    int*   aux     = (int*)  alloc(256 * 4);
    int*   row_off = (int*)  alloc((size_t)(n + 1) * 4);
    int*   cursor  = (int*)  alloc((size_t)n * 4);
    int*   ssrc    = (int*)  alloc((size_t)e * 4);
    float* snorm   = (float*)alloc((size_t)e * 4);
    float* h1      = (float*)alloc((size_t)n * gnn_f * 4);
    float* a1      = (float*)alloc((size_t)n * gnn_f * 4);
    float* h2      = (float*)alloc((size_t)n * out_f * 4);
    (void)ws_size;

    const int eb = (e + 255) / 256;
    const int nb256 = (n + 255) / 256;
    const int nchunks = (n + 1023) / 1024;

    // degrees + dinv
    hipMemsetAsync(deg_cnt, 0, (size_t)n * 4, stream);
    count_deg<<<eb, 256, 0, stream>>>(dst, e, deg_cnt);
    compute_dinv<<<nb256, 256, 0, stream>>>(deg_cnt, dinv, n);

    // exclusive scan -> row_off, cursor
    scan_a<<<nchunks, 256, 0, stream>>>(deg_cnt, part, aux, n);
    scan_b<<<1, 256, 0, stream>>>(aux, nchunks, &row_off[n]);
    scan_c<<<nb256, 256, 0, stream>>>(part, aux, row_off, cursor, n);

    // CSR fill (slot order nondeterministic; fp32 sum tolerant)
    fill_csr<<<eb, 256, 0, stream>>>(src, dst, e, dinv, cursor, ssrc, snorm);

    // layer 1: h1 = x @ W1 ; a1 = relu(Â h1 + b1)
    gemm_xw<128, 64><<<(n + 15) / 16, 256, 0, stream>>>(x, W1, h1, n);
    aggregate<64, true><<<(n + 3) / 4, 256, 0, stream>>>(h1, dinv, row_off, ssrc, snorm, b1, a1, n);

    // layer 2: h2 = a1 @ W2 ; out = Â h2 + b2
    gemm_xw<64, 40><<<(n + 15) / 16, 256, 0, stream>>>(a1, W2, h2, n);
    aggregate<40, false><<<(n + 3) / 4, 256, 0, stream>>>(h2, dinv, row_off, ssrc, snorm, b2, (float*)d_out, n);
}

// Round 2
// 695.557 us; speedup vs baseline: 6.2062x; 6.2062x over previous
//
#include <hip/hip_runtime.h>

// ---------------------------------------------------------------------------
// Two-layer GCN: out = Â(relu(Â(X W1) + b1) W2) + b2, Â = sym-norm adj + self loops
// CSR-by-dst built once per call (deg -> scan -> fill), reused for both layers.
// Aggregation = wave-per-node gather (lane = feature), no output atomics.
// R1 fix: gemm guarded-ternary float4 loads caused alloca->scratch spills
// (6.5 GB write traffic). Now: unconditional loads via hoisted clamped row
// pointers, 32 rows/block (100000 % 32 == 0), static-index unrolled arrays.
// ---------------------------------------------------------------------------

__global__ __launch_bounds__(256) void count_deg(const int* __restrict__ dst, int e,
                                                 int* __restrict__ deg) {
    int i = blockIdx.x * blockDim.x + threadIdx.x;
    if (i < e) atomicAdd(&deg[dst[i]], 1);
}

__global__ __launch_bounds__(256) void compute_dinv(const int* __restrict__ deg,
                                                    float* __restrict__ dinv, int n) {
    int i = blockIdx.x * blockDim.x + threadIdx.x;
    if (i < n) dinv[i] = rsqrtf((float)deg[i] + 1.0f);  // +1 = self loop
}

// ---- 3-phase exclusive scan over n ints (chunk = 1024 per block) ----------
__global__ __launch_bounds__(256) void scan_a(const int* __restrict__ in, int* __restrict__ part,
                                              int* __restrict__ aux, int n) {
    __shared__ int lds[256];
    int tid = threadIdx.x;
    int base = blockIdx.x * 1024 + tid * 4;
    int v0 = (base + 0 < n) ? in[base + 0] : 0;
    int v1 = (base + 1 < n) ? in[base + 1] : 0;
    int v2 = (base + 2 < n) ? in[base + 2] : 0;
    int v3 = (base + 3 < n) ? in[base + 3] : 0;
    int s = v0 + v1 + v2 + v3;
    lds[tid] = s;
    __syncthreads();
    for (int off = 1; off < 256; off <<= 1) {
        int t = (tid >= off) ? lds[tid - off] : 0;
        __syncthreads();
        lds[tid] += t;
        __syncthreads();
    }
    int excl = lds[tid] - s;
    if (base + 0 < n) part[base + 0] = excl;
    if (base + 1 < n) part[base + 1] = excl + v0;
    if (base + 2 < n) part[base + 2] = excl + v0 + v1;
    if (base + 3 < n) part[base + 3] = excl + v0 + v1 + v2;
    if (tid == 255) aux[blockIdx.x] = lds[255];
}

__global__ __launch_bounds__(256) void scan_b(int* __restrict__ aux, int nb,
                                              int* __restrict__ total_out) {
    __shared__ int lds[256];
    int tid = threadIdx.x;
    int v = (tid < nb) ? aux[tid] : 0;
    lds[tid] = v;
    __syncthreads();
    for (int off = 1; off < 256; off <<= 1) {
        int t = (tid >= off) ? lds[tid - off] : 0;
        __syncthreads();
        lds[tid] += t;
        __syncthreads();
    }
    if (tid < nb) aux[tid] = lds[tid] - v;
    if (tid == 255) *total_out = lds[255];
}

__global__ __launch_bounds__(256) void scan_c(const int* __restrict__ part,
                                              const int* __restrict__ aux,
                                              int* __restrict__ row_off,
                                              int* __restrict__ cursor, int n) {
    int i = blockIdx.x * blockDim.x + threadIdx.x;
    if (i < n) {
        int v = part[i] + aux[i >> 10];
        row_off[i] = v;
        cursor[i] = v;
    }
}

// ---- CSR fill: slot via atomic cursor; precompute edge norm ---------------
__global__ __launch_bounds__(256) void fill_csr(const int* __restrict__ src,
                                                const int* __restrict__ dst, int e,
                                                const float* __restrict__ dinv,
                                                int* __restrict__ cursor,
                                                int* __restrict__ ssrc,
                                                float* __restrict__ snorm) {
    int i = blockIdx.x * blockDim.x + threadIdx.x;
    if (i < e) {
        int s = src[i], d = dst[i];
        int p = atomicAdd(&cursor[d], 1);
        ssrc[p]  = s;
        snorm[p] = dinv[s] * dinv[d];
    }
}

// ---- GEMM H = X(NxK) * W(KxM), W staged fully in LDS ----------------------
// block: 256 threads = 4 waves; 32 rows per block, thread: 8 rows x 1 col.
// NO conditional float4 loads (scratch-spill hazard) — row ptrs hoisted+clamped.
template <int K, int M>
__global__ __launch_bounds__(256) void gemm_xw(const float* __restrict__ X,
                                               const float* __restrict__ W,
                                               float* __restrict__ H, int n) {
    __shared__ float w[K * M];
    int tid = threadIdx.x;
    for (int idx = tid; idx < K * M; idx += 256) w[idx] = W[idx];
    __syncthreads();
    int lane = tid & 63;
    int ty   = tid >> 6;                     // 0..3
    int r0   = blockIdx.x * 32 + ty * 8;     // 8 consecutive rows per thread

    const float* xp[8];
    #pragma unroll
    for (int r = 0; r < 8; ++r) {
        int rr = r0 + r; rr = rr < n - 1 ? rr : n - 1;   // clamp (no-op when n%32==0)
        xp[r] = X + (size_t)rr * K;
    }

    float acc[8];
    #pragma unroll
    for (int r = 0; r < 8; ++r) acc[r] = 0.f;

    for (int k = 0; k < K; k += 4) {
        float w0 = w[(k + 0) * M + lane];
        float w1 = w[(k + 1) * M + lane];
        float w2 = w[(k + 2) * M + lane];
        float w3 = w[(k + 3) * M + lane];
        #pragma unroll
        for (int r = 0; r < 8; ++r) {
            float4 xv = *reinterpret_cast<const float4*>(xp[r] + k);
            acc[r] = fmaf(xv.w, w3, fmaf(xv.z, w2, fmaf(xv.y, w1, fmaf(xv.x, w0, acc[r]))));
        }
    }

    if (lane < M) {
        #pragma unroll
        for (int r = 0; r < 8; ++r) {
            int rr = r0 + r;
            if (rr < n) H[(size_t)rr * M + lane] = acc[r];
        }
    }
}

// ---- Aggregation: out[i] = [relu](b + dinv[i]^2 h[i] + sum_e norm_e h[src_e])
// wave per node, lane = feature; edge loop unrolled x4 for 4 gathers in flight
template <int M, bool RELU>
__global__ __launch_bounds__(256) void aggregate(const float* __restrict__ H,
                                                 const float* __restrict__ dinv,
                                                 const int* __restrict__ row_off,
                                                 const int* __restrict__ ssrc,
                                                 const float* __restrict__ snorm,
                                                 const float* __restrict__ bias,
                                                 float* __restrict__ out, int n) {
    int wid  = (blockIdx.x * blockDim.x + threadIdx.x) >> 6;
    int lane = threadIdx.x & 63;
    if (wid >= n) return;
    float di = dinv[wid];
    float hv = (lane < M) ? H[(size_t)wid * M + lane] : 0.f;
    float acc = di * di * hv;
    int e0 = row_off[wid], e1 = row_off[wid + 1];
    int e = e0;
    for (; e + 4 <= e1; e += 4) {
        int   s0 = ssrc[e + 0], s1 = ssrc[e + 1], s2 = ssrc[e + 2], s3 = ssrc[e + 3];
        float n0 = snorm[e + 0], n1 = snorm[e + 1], n2 = snorm[e + 2], n3 = snorm[e + 3];
        if (lane < M) {
            float g0 = H[(size_t)s0 * M + lane];
            float g1 = H[(size_t)s1 * M + lane];
            float g2 = H[(size_t)s2 * M + lane];
            float g3 = H[(size_t)s3 * M + lane];
            acc = fmaf(n0, g0, acc);
            acc = fmaf(n1, g1, acc);
            acc = fmaf(n2, g2, acc);
            acc = fmaf(n3, g3, acc);
        }
    }
    for (; e < e1; ++e) {
        int s = ssrc[e];
        float nm = snorm[e];
        if (lane < M) acc = fmaf(nm, H[(size_t)s * M + lane], acc);
    }
    if (lane < M) {
        float o = acc + bias[lane];
        if (RELU) o = fmaxf(o, 0.f);
        out[(size_t)wid * M + lane] = o;
    }
}

// ---------------------------------------------------------------------------
extern "C" void kernel_launch(void* const* d_in, const int* in_sizes, int n_in,
                              void* d_out, int out_size, void* d_ws, size_t ws_size,
                              hipStream_t stream) {
    const float* x  = (const float*)d_in[0];
    const int*   ei = (const int*)d_in[1];
    const float* W1 = (const float*)d_in[2];
    const float* b1 = (const float*)d_in[3];
    const float* W2 = (const float*)d_in[4];
    const float* b2 = (const float*)d_in[5];

    const int gnn_f = in_sizes[3];            // 64
    const int out_f = in_sizes[5];            // 40
    const int in_f  = in_sizes[2] / gnn_f;    // 128
    const int e     = in_sizes[1] / 2;        // 1,600,000
    const int n     = in_sizes[0] / in_f;     // 100,000

    const int* src = ei;
    const int* dst = ei + e;

    // ---- workspace partition (256B aligned) ----
    char* base = (char*)d_ws;
    size_t off = 0;
    auto alloc = [&](size_t bytes) -> char* {
        char* p = base + off;
        off = (off + bytes + 255) & ~(size_t)255;
        return p;
    };
    int*   deg_cnt = (int*)  alloc((size_t)n * 4);
    float* dinv    = (float*)alloc((size_t)n * 4);
    int*   part    = (int*)  alloc((size_t)n * 4);
    int*   aux     = (int*)  alloc(256 * 4);
    int*   row_off = (int*)  alloc((size_t)(n + 1) * 4);
    int*   cursor  = (int*)  alloc((size_t)n * 4);
    int*   ssrc    = (int*)  alloc((size_t)e * 4);
    float* snorm   = (float*)alloc((size_t)e * 4);
    float* h1      = (float*)alloc((size_t)n * gnn_f * 4);
    float* a1      = (float*)alloc((size_t)n * gnn_f * 4);
    float* h2      = (float*)alloc((size_t)n * out_f * 4);
    (void)ws_size;

    const int eb = (e + 255) / 256;
    const int nb256 = (n + 255) / 256;
    const int nchunks = (n + 1023) / 1024;

    // degrees + dinv
    hipMemsetAsync(deg_cnt, 0, (size_t)n * 4, stream);
    count_deg<<<eb, 256, 0, stream>>>(dst, e, deg_cnt);
    compute_dinv<<<nb256, 256, 0, stream>>>(deg_cnt, dinv, n);

    // exclusive scan -> row_off, cursor
    scan_a<<<nchunks, 256, 0, stream>>>(deg_cnt, part, aux, n);
    scan_b<<<1, 256, 0, stream>>>(aux, nchunks, &row_off[n]);
    scan_c<<<nb256, 256, 0, stream>>>(part, aux, row_off, cursor, n);

    // CSR fill (slot order nondeterministic; fp32 sum tolerant)
    fill_csr<<<eb, 256, 0, stream>>>(src, dst, e, dinv, cursor, ssrc, snorm);

    // layer 1: h1 = x @ W1 ; a1 = relu(Â h1 + b1)
    gemm_xw<128, 64><<<(n + 31) / 32, 256, 0, stream>>>(x, W1, h1, n);
    aggregate<64, true><<<(n + 3) / 4, 256, 0, stream>>>(h1, dinv, row_off, ssrc, snorm, b1, a1, n);

    // layer 2: h2 = a1 @ W2 ; out = Â h2 + b2
    gemm_xw<64, 40><<<(n + 31) / 32, 256, 0, stream>>>(a1, W2, h2, n);
    aggregate<40, false><<<(n + 3) / 4, 256, 0, stream>>>(h2, dinv, row_off, ssrc, snorm, b2, (float*)d_out, n);
}

// Round 3
// 489.707 us; speedup vs baseline: 8.8150x; 1.4204x over previous
//
#include <hip/hip_runtime.h>

// ---------------------------------------------------------------------------
// Two-layer GCN: out = Â(relu(Â(X W1) + b1) W2) + b2, Â = sym-norm adj + self loops
// CSR-by-dst built once per call (deg -> scan -> fill), reused for both layers.
// Aggregation = wave-per-node gather (lane = feature), no output atomics.
// R2 fix: old gemm had lane-invariant (broadcast) X loads -> 16B/instr, plus
// full k-unroll -> 256 VGPR + scratch spill (147 MB writes). Now: LDS-staged
// register-tiled GEMM, 64x64 block tile, 4x4 per-thread tile with stride-16
// row/col mapping (bank-conflict-free), odd granule stride, unroll capped.
// ---------------------------------------------------------------------------

__global__ __launch_bounds__(256) void count_deg(const int* __restrict__ dst, int e,
                                                 int* __restrict__ deg) {
    int i = blockIdx.x * blockDim.x + threadIdx.x;
    if (i < e) atomicAdd(&deg[dst[i]], 1);
}

__global__ __launch_bounds__(256) void compute_dinv(const int* __restrict__ deg,
                                                    float* __restrict__ dinv, int n) {
    int i = blockIdx.x * blockDim.x + threadIdx.x;
    if (i < n) dinv[i] = rsqrtf((float)deg[i] + 1.0f);  // +1 = self loop
}

// ---- 3-phase exclusive scan over n ints (chunk = 1024 per block) ----------
__global__ __launch_bounds__(256) void scan_a(const int* __restrict__ in, int* __restrict__ part,
                                              int* __restrict__ aux, int n) {
    __shared__ int lds[256];
    int tid = threadIdx.x;
    int base = blockIdx.x * 1024 + tid * 4;
    int v0 = (base + 0 < n) ? in[base + 0] : 0;
    int v1 = (base + 1 < n) ? in[base + 1] : 0;
    int v2 = (base + 2 < n) ? in[base + 2] : 0;
    int v3 = (base + 3 < n) ? in[base + 3] : 0;
    int s = v0 + v1 + v2 + v3;
    lds[tid] = s;
    __syncthreads();
    for (int off = 1; off < 256; off <<= 1) {
        int t = (tid >= off) ? lds[tid - off] : 0;
        __syncthreads();
        lds[tid] += t;
        __syncthreads();
    }
    int excl = lds[tid] - s;
    if (base + 0 < n) part[base + 0] = excl;
    if (base + 1 < n) part[base + 1] = excl + v0;
    if (base + 2 < n) part[base + 2] = excl + v0 + v1;
    if (base + 3 < n) part[base + 3] = excl + v0 + v1 + v2;
    if (tid == 255) aux[blockIdx.x] = lds[255];
}

__global__ __launch_bounds__(256) void scan_b(int* __restrict__ aux, int nb,
                                              int* __restrict__ total_out) {
    __shared__ int lds[256];
    int tid = threadIdx.x;
    int v = (tid < nb) ? aux[tid] : 0;
    lds[tid] = v;
    __syncthreads();
    for (int off = 1; off < 256; off <<= 1) {
        int t = (tid >= off) ? lds[tid - off] : 0;
        __syncthreads();
        lds[tid] += t;
        __syncthreads();
    }
    if (tid < nb) aux[tid] = lds[tid] - v;
    if (tid == 255) *total_out = lds[255];
}

__global__ __launch_bounds__(256) void scan_c(const int* __restrict__ part,
                                              const int* __restrict__ aux,
                                              int* __restrict__ row_off,
                                              int* __restrict__ cursor, int n) {
    int i = blockIdx.x * blockDim.x + threadIdx.x;
    if (i < n) {
        int v = part[i] + aux[i >> 10];
        row_off[i] = v;
        cursor[i] = v;
    }
}

// ---- CSR fill: slot via atomic cursor; precompute edge norm ---------------
__global__ __launch_bounds__(256) void fill_csr(const int* __restrict__ src,
                                                const int* __restrict__ dst, int e,
                                                const float* __restrict__ dinv,
                                                int* __restrict__ cursor,
                                                int* __restrict__ ssrc,
                                                float* __restrict__ snorm) {
    int i = blockIdx.x * blockDim.x + threadIdx.x;
    if (i < e) {
        int s = src[i], d = dst[i];
        int p = atomicAdd(&cursor[d], 1);
        ssrc[p]  = s;
        snorm[p] = dinv[s] * dinv[d];
    }
}

// ---- GEMM H = X(NxK) * W(KxM): LDS-staged, register-tiled -----------------
// Block = 256 threads (tr=tid>>4 in 0..15, tc=tid&15), computes 64 rows x 64
// cols (W zero-padded to 64 cols). Thread tile: rows {tr+16i}, cols {tc+16j}.
// LDS granule stride SG = K/4+1 (odd) -> xs reads conflict-free, wt reads
// 2-way (free). K-loop unroll capped at 2 to keep VGPRs ~100 (no spills).
template <int K, int M>
__global__ __launch_bounds__(256) void gemm_xw(const float* __restrict__ X,
                                               const float* __restrict__ W,
                                               float* __restrict__ H, int n) {
    constexpr int KQ = K / 4;       // float4 granules per row (32 or 16)
    constexpr int SG = KQ + 1;      // padded LDS stride in granules (odd)
    __shared__ float4 xs[64 * SG];
    __shared__ float4 wt[64 * SG];

    const int tid = threadIdx.x;
    const int r0  = blockIdx.x * 64;

    // stage W transposed + zero-pad cols to 64: wt[m][kq] = W[4kq..4kq+3][m]
    for (int idx = tid; idx < 64 * KQ; idx += 256) {
        int m  = idx / KQ;          // KQ is a power of two
        int kq = idx & (KQ - 1);
        float4 v = make_float4(0.f, 0.f, 0.f, 0.f);
        if (m < M) {
            int k = kq * 4;
            v.x = W[(k + 0) * M + m];
            v.y = W[(k + 1) * M + m];
            v.z = W[(k + 2) * M + m];
            v.w = W[(k + 3) * M + m];
        }
        wt[m * SG + kq] = v;
    }
    // stage X rows r0..r0+63 (clamped; stores guarded)
    for (int idx = tid; idx < 64 * KQ; idx += 256) {
        int row = idx / KQ;
        int kq  = idx & (KQ - 1);
        int rr  = r0 + row; rr = rr < n ? rr : n - 1;
        xs[row * SG + kq] = *reinterpret_cast<const float4*>(&X[(size_t)rr * K + kq * 4]);
    }
    __syncthreads();

    const int tc = tid & 15;
    const int tr = tid >> 4;

    float acc[4][4];
    #pragma unroll
    for (int i = 0; i < 4; ++i)
        #pragma unroll
        for (int j = 0; j < 4; ++j) acc[i][j] = 0.f;

    #pragma unroll 2
    for (int kq = 0; kq < KQ; ++kq) {
        float4 xv[4], wv[4];
        #pragma unroll
        for (int i = 0; i < 4; ++i) xv[i] = xs[(tr + 16 * i) * SG + kq];
        #pragma unroll
        for (int j = 0; j < 4; ++j) wv[j] = wt[(tc + 16 * j) * SG + kq];
        #pragma unroll
        for (int i = 0; i < 4; ++i)
            #pragma unroll
            for (int j = 0; j < 4; ++j) {
                acc[i][j] = fmaf(xv[i].x, wv[j].x, acc[i][j]);
                acc[i][j] = fmaf(xv[i].y, wv[j].y, acc[i][j]);
                acc[i][j] = fmaf(xv[i].z, wv[j].z, acc[i][j]);
                acc[i][j] = fmaf(xv[i].w, wv[j].w, acc[i][j]);
            }
    }

    #pragma unroll
    for (int i = 0; i < 4; ++i) {
        int row = r0 + tr + 16 * i;
        if (row < n) {
            #pragma unroll
            for (int j = 0; j < 4; ++j) {
                int col = tc + 16 * j;
                if (col < M) H[(size_t)row * M + col] = acc[i][j];
            }
        }
    }
}

// ---- Aggregation: out[i] = [relu](b + dinv[i]^2 h[i] + sum_e norm_e h[src_e])
// wave per node, lane = feature; edge loop unrolled x4 for 4 gathers in flight
template <int M, bool RELU>
__global__ __launch_bounds__(256) void aggregate(const float* __restrict__ H,
                                                 const float* __restrict__ dinv,
                                                 const int* __restrict__ row_off,
                                                 const int* __restrict__ ssrc,
                                                 const float* __restrict__ snorm,
                                                 const float* __restrict__ bias,
                                                 float* __restrict__ out, int n) {
    int wid  = (blockIdx.x * blockDim.x + threadIdx.x) >> 6;
    int lane = threadIdx.x & 63;
    if (wid >= n) return;
    float di = dinv[wid];
    float hv = (lane < M) ? H[(size_t)wid * M + lane] : 0.f;
    float acc = di * di * hv;
    int e0 = row_off[wid], e1 = row_off[wid + 1];
    int e = e0;
    for (; e + 4 <= e1; e += 4) {
        int   s0 = ssrc[e + 0], s1 = ssrc[e + 1], s2 = ssrc[e + 2], s3 = ssrc[e + 3];
        float n0 = snorm[e + 0], n1 = snorm[e + 1], n2 = snorm[e + 2], n3 = snorm[e + 3];
        if (lane < M) {
            float g0 = H[(size_t)s0 * M + lane];
            float g1 = H[(size_t)s1 * M + lane];
            float g2 = H[(size_t)s2 * M + lane];
            float g3 = H[(size_t)s3 * M + lane];
            acc = fmaf(n0, g0, acc);
            acc = fmaf(n1, g1, acc);
            acc = fmaf(n2, g2, acc);
            acc = fmaf(n3, g3, acc);
        }
    }
    for (; e < e1; ++e) {
        int s = ssrc[e];
        float nm = snorm[e];
        if (lane < M) acc = fmaf(nm, H[(size_t)s * M + lane], acc);
    }
    if (lane < M) {
        float o = acc + bias[lane];
        if (RELU) o = fmaxf(o, 0.f);
        out[(size_t)wid * M + lane] = o;
    }
}

// ---------------------------------------------------------------------------
extern "C" void kernel_launch(void* const* d_in, const int* in_sizes, int n_in,
                              void* d_out, int out_size, void* d_ws, size_t ws_size,
                              hipStream_t stream) {
    const float* x  = (const float*)d_in[0];
    const int*   ei = (const int*)d_in[1];
    const float* W1 = (const float*)d_in[2];
    const float* b1 = (const float*)d_in[3];
    const float* W2 = (const float*)d_in[4];
    const float* b2 = (const float*)d_in[5];

    const int gnn_f = in_sizes[3];            // 64
    const int out_f = in_sizes[5];            // 40
    const int in_f  = in_sizes[2] / gnn_f;    // 128
    const int e     = in_sizes[1] / 2;        // 1,600,000
    const int n     = in_sizes[0] / in_f;     // 100,000

    const int* src = ei;
    const int* dst = ei + e;

    // ---- workspace partition (256B aligned) ----
    char* base = (char*)d_ws;
    size_t off = 0;
    auto alloc = [&](size_t bytes) -> char* {
        char* p = base + off;
        off = (off + bytes + 255) & ~(size_t)255;
        return p;
    };
    int*   deg_cnt = (int*)  alloc((size_t)n * 4);
    float* dinv    = (float*)alloc((size_t)n * 4);
    int*   part    = (int*)  alloc((size_t)n * 4);
    int*   aux     = (int*)  alloc(256 * 4);
    int*   row_off = (int*)  alloc((size_t)(n + 1) * 4);
    int*   cursor  = (int*)  alloc((size_t)n * 4);
    int*   ssrc    = (int*)  alloc((size_t)e * 4);
    float* snorm   = (float*)alloc((size_t)e * 4);
    float* h1      = (float*)alloc((size_t)n * gnn_f * 4);
    float* a1      = (float*)alloc((size_t)n * gnn_f * 4);
    float* h2      = (float*)alloc((size_t)n * out_f * 4);
    (void)ws_size;

    const int eb = (e + 255) / 256;
    const int nb256 = (n + 255) / 256;
    const int nchunks = (n + 1023) / 1024;

    // degrees + dinv
    hipMemsetAsync(deg_cnt, 0, (size_t)n * 4, stream);
    count_deg<<<eb, 256, 0, stream>>>(dst, e, deg_cnt);
    compute_dinv<<<nb256, 256, 0, stream>>>(deg_cnt, dinv, n);

    // exclusive scan -> row_off, cursor
    scan_a<<<nchunks, 256, 0, stream>>>(deg_cnt, part, aux, n);
    scan_b<<<1, 256, 0, stream>>>(aux, nchunks, &row_off[n]);
    scan_c<<<nb256, 256, 0, stream>>>(part, aux, row_off, cursor, n);

    // CSR fill (slot order nondeterministic; fp32 sum tolerant)
    fill_csr<<<eb, 256, 0, stream>>>(src, dst, e, dinv, cursor, ssrc, snorm);

    // layer 1: h1 = x @ W1 ; a1 = relu(Â h1 + b1)
    gemm_xw<128, 64><<<(n + 63) / 64, 256, 0, stream>>>(x, W1, h1, n);
    aggregate<64, true><<<(n + 3) / 4, 256, 0, stream>>>(h1, dinv, row_off, ssrc, snorm, b1, a1, n);

    // layer 2: h2 = a1 @ W2 ; out = Â h2 + b2
    gemm_xw<64, 40><<<(n + 63) / 64, 256, 0, stream>>>(a1, W2, h2, n);
    aggregate<40, false><<<(n + 3) / 4, 256, 0, stream>>>(h2, dinv, row_off, ssrc, snorm, b2, (float*)d_out, n);
}

// Round 4
// 397.021 us; speedup vs baseline: 10.8729x; 1.2335x over previous
//
#include <hip/hip_runtime.h>

// ---------------------------------------------------------------------------
// Two-layer GCN: out = Â(relu(Â(X W1) + b1) W2) + b2, Â = sym-norm adj + self loops
// CSR-by-dst built once per call: count (stores per-edge rank) -> scan -> fill
// (atomic-free single 4B scatter). No snorm table: norm computed on the fly in
// aggregate from the L2-hot dinv table. Aggregation = wave-per-node, half-wave
// edge-parallel float2 gather (lanes 0-31 even edges / 32-63 odd edges),
// combined via __shfl_xor(…,32). No output atomics anywhere.
// ---------------------------------------------------------------------------

__global__ __launch_bounds__(256) void count_deg_rank(const int* __restrict__ dst, int e,
                                                      int* __restrict__ deg,
                                                      int* __restrict__ rank) {
    int i = blockIdx.x * blockDim.x + threadIdx.x;
    if (i < e) rank[i] = atomicAdd(&deg[dst[i]], 1);
}

__global__ __launch_bounds__(256) void compute_dinv(const int* __restrict__ deg,
                                                    float* __restrict__ dinv, int n) {
    int i = blockIdx.x * blockDim.x + threadIdx.x;
    if (i < n) dinv[i] = rsqrtf((float)deg[i] + 1.0f);  // +1 = self loop
}

// ---- 3-phase exclusive scan over n ints (chunk = 1024 per block) ----------
__global__ __launch_bounds__(256) void scan_a(const int* __restrict__ in, int* __restrict__ part,
                                              int* __restrict__ aux, int n) {
    __shared__ int lds[256];
    int tid = threadIdx.x;
    int base = blockIdx.x * 1024 + tid * 4;
    int v0 = (base + 0 < n) ? in[base + 0] : 0;
    int v1 = (base + 1 < n) ? in[base + 1] : 0;
    int v2 = (base + 2 < n) ? in[base + 2] : 0;
    int v3 = (base + 3 < n) ? in[base + 3] : 0;
    int s = v0 + v1 + v2 + v3;
    lds[tid] = s;
    __syncthreads();
    for (int off = 1; off < 256; off <<= 1) {
        int t = (tid >= off) ? lds[tid - off] : 0;
        __syncthreads();
        lds[tid] += t;
        __syncthreads();
    }
    int excl = lds[tid] - s;
    if (base + 0 < n) part[base + 0] = excl;
    if (base + 1 < n) part[base + 1] = excl + v0;
    if (base + 2 < n) part[base + 2] = excl + v0 + v1;
    if (base + 3 < n) part[base + 3] = excl + v0 + v1 + v2;
    if (tid == 255) aux[blockIdx.x] = lds[255];
}

__global__ __launch_bounds__(256) void scan_b(int* __restrict__ aux, int nb,
                                              int* __restrict__ total_out) {
    __shared__ int lds[256];
    int tid = threadIdx.x;
    int v = (tid < nb) ? aux[tid] : 0;
    lds[tid] = v;
    __syncthreads();
    for (int off = 1; off < 256; off <<= 1) {
        int t = (tid >= off) ? lds[tid - off] : 0;
        __syncthreads();
        lds[tid] += t;
        __syncthreads();
    }
    if (tid < nb) aux[tid] = lds[tid] - v;
    if (tid == 255) *total_out = lds[255];
}

__global__ __launch_bounds__(256) void scan_c(const int* __restrict__ part,
                                              const int* __restrict__ aux,
                                              int* __restrict__ row_off, int n) {
    int i = blockIdx.x * blockDim.x + threadIdx.x;
    if (i < n) row_off[i] = part[i] + aux[i >> 10];
}

// ---- CSR fill: atomic-free, single 4B scatter per edge --------------------
__global__ __launch_bounds__(256) void fill_src(const int* __restrict__ src,
                                                const int* __restrict__ dst,
                                                const int* __restrict__ rank,
                                                const int* __restrict__ row_off, int e,
                                                int* __restrict__ ssrc) {
    int i = blockIdx.x * blockDim.x + threadIdx.x;
    if (i < e) ssrc[row_off[dst[i]] + rank[i]] = src[i];
}

// ---- GEMM H = X(NxK) * W(KxM): LDS-staged, register-tiled -----------------
// Block = 256 threads, 64 rows x 64 cols (W zero-padded to 64 cols).
// Thread tile 4x4, stride-16 row/col mapping; odd LDS granule stride.
template <int K, int M>
__global__ __launch_bounds__(256) void gemm_xw(const float* __restrict__ X,
                                               const float* __restrict__ W,
                                               float* __restrict__ H, int n) {
    constexpr int KQ = K / 4;
    constexpr int SG = KQ + 1;
    __shared__ float4 xs[64 * SG];
    __shared__ float4 wt[64 * SG];

    const int tid = threadIdx.x;
    const int r0  = blockIdx.x * 64;

    for (int idx = tid; idx < 64 * KQ; idx += 256) {
        int m  = idx / KQ;
        int kq = idx & (KQ - 1);
        float4 v = make_float4(0.f, 0.f, 0.f, 0.f);
        if (m < M) {
            int k = kq * 4;
            v.x = W[(k + 0) * M + m];
            v.y = W[(k + 1) * M + m];
            v.z = W[(k + 2) * M + m];
            v.w = W[(k + 3) * M + m];
        }
        wt[m * SG + kq] = v;
    }
    for (int idx = tid; idx < 64 * KQ; idx += 256) {
        int row = idx / KQ;
        int kq  = idx & (KQ - 1);
        int rr  = r0 + row; rr = rr < n ? rr : n - 1;
        xs[row * SG + kq] = *reinterpret_cast<const float4*>(&X[(size_t)rr * K + kq * 4]);
    }
    __syncthreads();

    const int tc = tid & 15;
    const int tr = tid >> 4;

    float acc[4][4];
    #pragma unroll
    for (int i = 0; i < 4; ++i)
        #pragma unroll
        for (int j = 0; j < 4; ++j) acc[i][j] = 0.f;

    #pragma unroll 2
    for (int kq = 0; kq < KQ; ++kq) {
        float4 xv[4], wv[4];
        #pragma unroll
        for (int i = 0; i < 4; ++i) xv[i] = xs[(tr + 16 * i) * SG + kq];
        #pragma unroll
        for (int j = 0; j < 4; ++j) wv[j] = wt[(tc + 16 * j) * SG + kq];
        #pragma unroll
        for (int i = 0; i < 4; ++i)
            #pragma unroll
            for (int j = 0; j < 4; ++j) {
                acc[i][j] = fmaf(xv[i].x, wv[j].x, acc[i][j]);
                acc[i][j] = fmaf(xv[i].y, wv[j].y, acc[i][j]);
                acc[i][j] = fmaf(xv[i].z, wv[j].z, acc[i][j]);
                acc[i][j] = fmaf(xv[i].w, wv[j].w, acc[i][j]);
            }
    }

    #pragma unroll
    for (int i = 0; i < 4; ++i) {
        int row = r0 + tr + 16 * i;
        if (row < n) {
            #pragma unroll
            for (int j = 0; j < 4; ++j) {
                int col = tc + 16 * j;
                if (col < M) H[(size_t)row * M + col] = acc[i][j];
            }
        }
    }
}

// ---- Aggregation: out[i] = [relu](b + dinv[i]^2 h[i] + sum_e dinv[s]dinv[i] h[s])
// wave per node; half-wave edge-parallel: lanes 0-31 even edges, 32-63 odd.
// Each lane owns a float2 feature pair; halves combined via __shfl_xor(.,32).
template <int M, bool RELU>
__global__ __launch_bounds__(256) void aggregate(const float* __restrict__ H,
                                                 const float* __restrict__ dinv,
                                                 const int* __restrict__ row_off,
                                                 const int* __restrict__ ssrc,
                                                 const float* __restrict__ bias,
                                                 float* __restrict__ out, int n) {
    constexpr int MH = M / 2;                      // float2 elems per row
    int wid  = (blockIdx.x * blockDim.x + threadIdx.x) >> 6;
    if (wid >= n) return;
    int lane = threadIdx.x & 63;
    int half = lane >> 5;
    int c    = lane & 31;
    int cc   = c < MH ? c : MH - 1;                // clamp: inactive lanes stay in-bounds
    const float2* __restrict__ H2 = (const float2*)H;

    float di = dinv[wid];
    float2 acc = make_float2(0.f, 0.f);
    int e0 = row_off[wid], e1 = row_off[wid + 1];

    int e = e0 + half;                             // this half's first edge
    for (; e + 6 < e1; e += 8) {                   // 4 edges per half per iter
        int s0 = ssrc[e + 0], s1 = ssrc[e + 2], s2 = ssrc[e + 4], s3 = ssrc[e + 6];
        float n0 = dinv[s0] * di, n1 = dinv[s1] * di,
              n2 = dinv[s2] * di, n3 = dinv[s3] * di;
        float2 g0 = H2[s0 * MH + cc];
        float2 g1 = H2[s1 * MH + cc];
        float2 g2 = H2[s2 * MH + cc];
        float2 g3 = H2[s3 * MH + cc];
        acc.x = fmaf(n0, g0.x, acc.x); acc.y = fmaf(n0, g0.y, acc.y);
        acc.x = fmaf(n1, g1.x, acc.x); acc.y = fmaf(n1, g1.y, acc.y);
        acc.x = fmaf(n2, g2.x, acc.x); acc.y = fmaf(n2, g2.y, acc.y);
        acc.x = fmaf(n3, g3.x, acc.x); acc.y = fmaf(n3, g3.y, acc.y);
    }
    for (; e < e1; e += 2) {
        int s = ssrc[e];
        float nm = dinv[s] * di;
        float2 g = H2[s * MH + cc];
        acc.x = fmaf(nm, g.x, acc.x); acc.y = fmaf(nm, g.y, acc.y);
    }

    // combine the two half-wave partial sums
    acc.x += __shfl_xor(acc.x, 32);
    acc.y += __shfl_xor(acc.y, 32);

    // self-loop + bias, store from half 0
    float2 hv = H2[wid * MH + cc];
    float2 bv = ((const float2*)bias)[cc];
    float o0 = fmaf(di * di, hv.x, acc.x) + bv.x;
    float o1 = fmaf(di * di, hv.y, acc.y) + bv.y;
    if (RELU) { o0 = fmaxf(o0, 0.f); o1 = fmaxf(o1, 0.f); }
    if (half == 0 && c < MH) {
        ((float2*)out)[wid * MH + c] = make_float2(o0, o1);
    }
}

// ---------------------------------------------------------------------------
extern "C" void kernel_launch(void* const* d_in, const int* in_sizes, int n_in,
                              void* d_out, int out_size, void* d_ws, size_t ws_size,
                              hipStream_t stream) {
    const float* x  = (const float*)d_in[0];
    const int*   ei = (const int*)d_in[1];
    const float* W1 = (const float*)d_in[2];
    const float* b1 = (const float*)d_in[3];
    const float* W2 = (const float*)d_in[4];
    const float* b2 = (const float*)d_in[5];

    const int gnn_f = in_sizes[3];            // 64
    const int out_f = in_sizes[5];            // 40
    const int in_f  = in_sizes[2] / gnn_f;    // 128
    const int e     = in_sizes[1] / 2;        // 1,600,000
    const int n     = in_sizes[0] / in_f;     // 100,000

    const int* src = ei;
    const int* dst = ei + e;

    // ---- workspace partition (256B aligned) ----
    char* base = (char*)d_ws;
    size_t off = 0;
    auto alloc = [&](size_t bytes) -> char* {
        char* p = base + off;
        off = (off + bytes + 255) & ~(size_t)255;
        return p;
    };
    int*   deg_cnt = (int*)  alloc((size_t)n * 4);
    float* dinv    = (float*)alloc((size_t)n * 4);
    int*   part    = (int*)  alloc((size_t)n * 4);
    int*   aux     = (int*)  alloc(256 * 4);
    int*   row_off = (int*)  alloc((size_t)(n + 1) * 4);
    int*   rank    = (int*)  alloc((size_t)e * 4);
    int*   ssrc    = (int*)  alloc((size_t)e * 4);
    float* h1      = (float*)alloc((size_t)n * gnn_f * 4);
    float* a1      = (float*)alloc((size_t)n * gnn_f * 4);
    float* h2      = (float*)alloc((size_t)n * out_f * 4);
    (void)ws_size;

    const int eb = (e + 255) / 256;
    const int nb256 = (n + 255) / 256;
    const int nchunks = (n + 1023) / 1024;

    // degrees (+ per-edge rank) + dinv
    hipMemsetAsync(deg_cnt, 0, (size_t)n * 4, stream);
    count_deg_rank<<<eb, 256, 0, stream>>>(dst, e, deg_cnt, rank);
    compute_dinv<<<nb256, 256, 0, stream>>>(deg_cnt, dinv, n);

    // exclusive scan -> row_off
    scan_a<<<nchunks, 256, 0, stream>>>(deg_cnt, part, aux, n);
    scan_b<<<1, 256, 0, stream>>>(aux, nchunks, &row_off[n]);
    scan_c<<<nb256, 256, 0, stream>>>(part, aux, row_off, n);

    // CSR fill: atomic-free single scatter
    fill_src<<<eb, 256, 0, stream>>>(src, dst, rank, row_off, e, ssrc);

    // layer 1: h1 = x @ W1 ; a1 = relu(Â h1 + b1)
    gemm_xw<128, 64><<<(n + 63) / 64, 256, 0, stream>>>(x, W1, h1, n);
    aggregate<64, true><<<(n + 3) / 4, 256, 0, stream>>>(h1, dinv, row_off, ssrc, b1, a1, n);

    // layer 2: h2 = a1 @ W2 ; out = Â h2 + b2
    gemm_xw<64, 40><<<(n + 63) / 64, 256, 0, stream>>>(a1, W2, h2, n);
    aggregate<40, false><<<(n + 3) / 4, 256, 0, stream>>>(h2, dinv, row_off, ssrc, b2, (float*)d_out, n);
}

// Round 5
// 371.534 us; speedup vs baseline: 11.6188x; 1.0686x over previous
//
#include <hip/hip_runtime.h>

// ---------------------------------------------------------------------------
// Two-layer GCN: out = Â(relu(Â(X W1) + b1) W2) + b2, Â = sym-norm adj + self loops
// CSR-by-dst built once per call: count (stores per-edge ushort rank) -> scan
// (fused dinv) -> atomic-free 4B scatter fill.
// R4->R5: aggregation was gather-bytes-bound (410 MB L1<->L2, 194 MB L2 miss).
// Now GEMM epilogue emits G = bf16(dinv[row] * h[row]) so the gather table is
// half the bytes AND pre-scaled: out = b + di*(G[i] + sum_e G[src_e]).
// M=64 aggregation: quarter-wave edge-parallel (16 lanes x 4 bf16 per row,
// 4 edges in flight), reduced via __shfl_xor(16|32). M=40: half-wave x 2 bf16.
// ---------------------------------------------------------------------------

__device__ inline float bflo(unsigned u) { return __uint_as_float(u << 16); }
__device__ inline float bfhi(unsigned u) { return __uint_as_float(u & 0xffff0000u); }
__device__ inline unsigned short f2bf(float x) {        // round-to-nearest-even
    unsigned u = __float_as_uint(x);
    return (unsigned short)((u + 0x7fff + ((u >> 16) & 1)) >> 16);
}

__global__ __launch_bounds__(256) void count_deg_rank(const int* __restrict__ dst, int e,
                                                      int* __restrict__ deg,
                                                      unsigned short* __restrict__ rank) {
    int i = blockIdx.x * blockDim.x + threadIdx.x;
    if (i < e) rank[i] = (unsigned short)atomicAdd(&deg[dst[i]], 1);
}

// ---- 3-phase exclusive scan over n ints (chunk = 1024 per block) ----------
__global__ __launch_bounds__(256) void scan_a(const int* __restrict__ in, int* __restrict__ part,
                                              int* __restrict__ aux, int n) {
    __shared__ int lds[256];
    int tid = threadIdx.x;
    int base = blockIdx.x * 1024 + tid * 4;
    int v0 = (base + 0 < n) ? in[base + 0] : 0;
    int v1 = (base + 1 < n) ? in[base + 1] : 0;
    int v2 = (base + 2 < n) ? in[base + 2] : 0;
    int v3 = (base + 3 < n) ? in[base + 3] : 0;
    int s = v0 + v1 + v2 + v3;
    lds[tid] = s;
    __syncthreads();
    for (int off = 1; off < 256; off <<= 1) {
        int t = (tid >= off) ? lds[tid - off] : 0;
        __syncthreads();
        lds[tid] += t;
        __syncthreads();
    }
    int excl = lds[tid] - s;
    if (base + 0 < n) part[base + 0] = excl;
    if (base + 1 < n) part[base + 1] = excl + v0;
    if (base + 2 < n) part[base + 2] = excl + v0 + v1;
    if (base + 3 < n) part[base + 3] = excl + v0 + v1 + v2;
    if (tid == 255) aux[blockIdx.x] = lds[255];
}

__global__ __launch_bounds__(256) void scan_b(int* __restrict__ aux, int nb,
                                              int* __restrict__ total_out) {
    __shared__ int lds[256];
    int tid = threadIdx.x;
    int v = (tid < nb) ? aux[tid] : 0;
    lds[tid] = v;
    __syncthreads();
    for (int off = 1; off < 256; off <<= 1) {
        int t = (tid >= off) ? lds[tid - off] : 0;
        __syncthreads();
        lds[tid] += t;
        __syncthreads();
    }
    if (tid < nb) aux[tid] = lds[tid] - v;
    if (tid == 255) *total_out = lds[255];
}

// scan_c fused with dinv computation
__global__ __launch_bounds__(256) void scan_c(const int* __restrict__ part,
                                              const int* __restrict__ aux,
                                              const int* __restrict__ deg,
                                              int* __restrict__ row_off,
                                              float* __restrict__ dinv, int n) {
    int i = blockIdx.x * blockDim.x + threadIdx.x;
    if (i < n) {
        row_off[i] = part[i] + aux[i >> 10];
        dinv[i] = rsqrtf((float)deg[i] + 1.0f);   // +1 = self loop
    }
}

// ---- CSR fill: atomic-free, single 4B scatter per edge --------------------
__global__ __launch_bounds__(256) void fill_src(const int* __restrict__ src,
                                                const int* __restrict__ dst,
                                                const unsigned short* __restrict__ rank,
                                                const int* __restrict__ row_off, int e,
                                                int* __restrict__ ssrc) {
    int i = blockIdx.x * blockDim.x + threadIdx.x;
    if (i < e) ssrc[row_off[dst[i]] + rank[i]] = src[i];
}

// ---- GEMM G = bf16(dinv * (X W)): LDS-staged, register-tiled --------------
// Block = 256 threads, 64 rows x 64 cols (W zero-padded to 64 cols).
// Thread tile 4x4, stride-16 row/col mapping; odd LDS granule stride.
template <int K, int M>
__global__ __launch_bounds__(256) void gemm_xw(const float* __restrict__ X,
                                               const float* __restrict__ W,
                                               const float* __restrict__ dinv,
                                               unsigned short* __restrict__ G, int n) {
    constexpr int KQ = K / 4;
    constexpr int SG = KQ + 1;
    __shared__ float4 xs[64 * SG];
    __shared__ float4 wt[64 * SG];

    const int tid = threadIdx.x;
    const int r0  = blockIdx.x * 64;

    for (int idx = tid; idx < 64 * KQ; idx += 256) {
        int m  = idx / KQ;
        int kq = idx & (KQ - 1);
        float4 v = make_float4(0.f, 0.f, 0.f, 0.f);
        if (m < M) {
            int k = kq * 4;
            v.x = W[(k + 0) * M + m];
            v.y = W[(k + 1) * M + m];
            v.z = W[(k + 2) * M + m];
            v.w = W[(k + 3) * M + m];
        }
        wt[m * SG + kq] = v;
    }
    for (int idx = tid; idx < 64 * KQ; idx += 256) {
        int row = idx / KQ;
        int kq  = idx & (KQ - 1);
        int rr  = r0 + row; rr = rr < n ? rr : n - 1;
        xs[row * SG + kq] = *reinterpret_cast<const float4*>(&X[(size_t)rr * K + kq * 4]);
    }
    __syncthreads();

    const int tc = tid & 15;
    const int tr = tid >> 4;

    float acc[4][4];
    #pragma unroll
    for (int i = 0; i < 4; ++i)
        #pragma unroll
        for (int j = 0; j < 4; ++j) acc[i][j] = 0.f;

    #pragma unroll 2
    for (int kq = 0; kq < KQ; ++kq) {
        float4 xv[4], wv[4];
        #pragma unroll
        for (int i = 0; i < 4; ++i) xv[i] = xs[(tr + 16 * i) * SG + kq];
        #pragma unroll
        for (int j = 0; j < 4; ++j) wv[j] = wt[(tc + 16 * j) * SG + kq];
        #pragma unroll
        for (int i = 0; i < 4; ++i)
            #pragma unroll
            for (int j = 0; j < 4; ++j) {
                acc[i][j] = fmaf(xv[i].x, wv[j].x, acc[i][j]);
                acc[i][j] = fmaf(xv[i].y, wv[j].y, acc[i][j]);
                acc[i][j] = fmaf(xv[i].z, wv[j].z, acc[i][j]);
                acc[i][j] = fmaf(xv[i].w, wv[j].w, acc[i][j]);
            }
    }

    #pragma unroll
    for (int i = 0; i < 4; ++i) {
        int row = r0 + tr + 16 * i;
        if (row < n) {
            float di = dinv[row];
            #pragma unroll
            for (int j = 0; j < 4; ++j) {
                int col = tc + 16 * j;
                if (col < M) G[(size_t)row * M + col] = f2bf(di * acc[i][j]);
            }
        }
    }
}

// ---- Aggregation M=64: out[i] = [relu](b + di*(G[i] + sum_e G[src_e])) ----
// wave per node; quarter-wave edge-parallel: quarter q handles edges e0+q+4k;
// lane owns 4 bf16 features (8B load). Reduce via __shfl_xor(16|32).
template <bool RELU>
__global__ __launch_bounds__(256) void aggregate64(const unsigned short* __restrict__ G,
                                                   const float* __restrict__ dinv,
                                                   const int* __restrict__ row_off,
                                                   const int* __restrict__ ssrc,
                                                   const float* __restrict__ bias,
                                                   float* __restrict__ out, int n) {
    int wid  = (blockIdx.x * blockDim.x + threadIdx.x) >> 6;
    if (wid >= n) return;
    int lane = threadIdx.x & 63;
    int q = lane >> 4;                 // 0..3: edge phase
    int c = lane & 15;                 // feature group: feats 4c..4c+3
    const uint2* __restrict__ G4 = (const uint2*)G;   // row stride 16

    float4 acc = make_float4(0.f, 0.f, 0.f, 0.f);
    int e0 = row_off[wid], e1 = row_off[wid + 1];

    int e = e0 + q;
    for (; e + 4 < e1; e += 8) {       // 2 edges per quarter per iter
        int s0 = ssrc[e], s1 = ssrc[e + 4];
        uint2 g0 = G4[(size_t)s0 * 16 + c];
        uint2 g1 = G4[(size_t)s1 * 16 + c];
        acc.x += bflo(g0.x); acc.y += bfhi(g0.x); acc.z += bflo(g0.y); acc.w += bfhi(g0.y);
        acc.x += bflo(g1.x); acc.y += bfhi(g1.x); acc.z += bflo(g1.y); acc.w += bfhi(g1.y);
    }
    if (e < e1) {
        int s = ssrc[e];
        uint2 g = G4[(size_t)s * 16 + c];
        acc.x += bflo(g.x); acc.y += bfhi(g.x); acc.z += bflo(g.y); acc.w += bfhi(g.y);
    }

    // combine the 4 quarter partial sums (same features across quarters)
    acc.x += __shfl_xor(acc.x, 16); acc.y += __shfl_xor(acc.y, 16);
    acc.z += __shfl_xor(acc.z, 16); acc.w += __shfl_xor(acc.w, 16);
    acc.x += __shfl_xor(acc.x, 32); acc.y += __shfl_xor(acc.y, 32);
    acc.z += __shfl_xor(acc.z, 32); acc.w += __shfl_xor(acc.w, 32);

    float di = dinv[wid];
    uint2 gs = G4[(size_t)wid * 16 + c];               // self loop: di*G[i]
    float4 bv = ((const float4*)bias)[c];
    float4 o;
    o.x = fmaf(di, acc.x + bflo(gs.x), bv.x);
    o.y = fmaf(di, acc.y + bfhi(gs.x), bv.y);
    o.z = fmaf(di, acc.z + bflo(gs.y), bv.z);
    o.w = fmaf(di, acc.w + bfhi(gs.y), bv.w);
    if (RELU) {
        o.x = fmaxf(o.x, 0.f); o.y = fmaxf(o.y, 0.f);
        o.z = fmaxf(o.z, 0.f); o.w = fmaxf(o.w, 0.f);
    }
    if (q == 0) ((float4*)out)[(size_t)wid * 16 + c] = o;
}

// ---- Aggregation M=40: half-wave edge-parallel, lane owns 2 bf16 feats ----
template <bool RELU>
__global__ __launch_bounds__(256) void aggregate40(const unsigned short* __restrict__ G,
                                                   const float* __restrict__ dinv,
                                                   const int* __restrict__ row_off,
                                                   const int* __restrict__ ssrc,
                                                   const float* __restrict__ bias,
                                                   float* __restrict__ out, int n) {
    constexpr int MH = 20;                            // uint granules per row
    int wid  = (blockIdx.x * blockDim.x + threadIdx.x) >> 6;
    if (wid >= n) return;
    int lane = threadIdx.x & 63;
    int half = lane >> 5;
    int c    = lane & 31;
    int cc   = c < MH ? c : MH - 1;                   // clamp: stay in bounds
    const unsigned* __restrict__ G2 = (const unsigned*)G;

    float2 acc = make_float2(0.f, 0.f);
    int e0 = row_off[wid], e1 = row_off[wid + 1];

    int e = e0 + half;
    for (; e + 2 < e1; e += 4) {                      // 2 edges per half per iter
        int s0 = ssrc[e], s1 = ssrc[e + 2];
        unsigned g0 = G2[(size_t)s0 * MH + cc];
        unsigned g1 = G2[(size_t)s1 * MH + cc];
        acc.x += bflo(g0); acc.y += bfhi(g0);
        acc.x += bflo(g1); acc.y += bfhi(g1);
    }
    if (e < e1) {
        unsigned g = G2[(size_t)ssrc[e] * MH + cc];
        acc.x += bflo(g); acc.y += bfhi(g);
    }

    acc.x += __shfl_xor(acc.x, 32);
    acc.y += __shfl_xor(acc.y, 32);

    float di = dinv[wid];
    unsigned gs = G2[(size_t)wid * MH + cc];
    float2 bv = ((const float2*)bias)[cc];
    float o0 = fmaf(di, acc.x + bflo(gs), bv.x);
    float o1 = fmaf(di, acc.y + bfhi(gs), bv.y);
    if (RELU) { o0 = fmaxf(o0, 0.f); o1 = fmaxf(o1, 0.f); }
    if (half == 0 && c < MH) {
        ((float2*)out)[(size_t)wid * MH + c] = make_float2(o0, o1);
    }
}

// ---------------------------------------------------------------------------
extern "C" void kernel_launch(void* const* d_in, const int* in_sizes, int n_in,
                              void* d_out, int out_size, void* d_ws, size_t ws_size,
                              hipStream_t stream) {
    const float* x  = (const float*)d_in[0];
    const int*   ei = (const int*)d_in[1];
    const float* W1 = (const float*)d_in[2];
    const float* b1 = (const float*)d_in[3];
    const float* W2 = (const float*)d_in[4];
    const float* b2 = (const float*)d_in[5];

    const int gnn_f = in_sizes[3];            // 64
    const int out_f = in_sizes[5];            // 40
    const int in_f  = in_sizes[2] / gnn_f;    // 128
    const int e     = in_sizes[1] / 2;        // 1,600,000
    const int n     = in_sizes[0] / in_f;     // 100,000

    const int* src = ei;
    const int* dst = ei + e;

    // ---- workspace partition (256B aligned) ----
    char* base = (char*)d_ws;
    size_t off = 0;
    auto alloc = [&](size_t bytes) -> char* {
        char* p = base + off;
        off = (off + bytes + 255) & ~(size_t)255;
        return p;
    };
    int*            deg_cnt = (int*)            alloc((size_t)n * 4);
    float*          dinv    = (float*)          alloc((size_t)n * 4);
    int*            part    = (int*)            alloc((size_t)n * 4);
    int*            aux     = (int*)            alloc(256 * 4);
    int*            row_off = (int*)            alloc((size_t)(n + 1) * 4);
    unsigned short* rank    = (unsigned short*) alloc((size_t)e * 2);
    int*            ssrc    = (int*)            alloc((size_t)e * 4);
    unsigned short* g1      = (unsigned short*) alloc((size_t)n * gnn_f * 2);
    float*          a1      = (float*)          alloc((size_t)n * gnn_f * 4);
    unsigned short* g2      = (unsigned short*) alloc((size_t)n * out_f * 2);
    (void)ws_size;

    const int eb = (e + 255) / 256;
    const int nb256 = (n + 255) / 256;
    const int nchunks = (n + 1023) / 1024;

    // degrees (+ per-edge rank)
    hipMemsetAsync(deg_cnt, 0, (size_t)n * 4, stream);
    count_deg_rank<<<eb, 256, 0, stream>>>(dst, e, deg_cnt, rank);

    // exclusive scan -> row_off (+ dinv fused into scan_c)
    scan_a<<<nchunks, 256, 0, stream>>>(deg_cnt, part, aux, n);
    scan_b<<<1, 256, 0, stream>>>(aux, nchunks, &row_off[n]);
    scan_c<<<nb256, 256, 0, stream>>>(part, aux, deg_cnt, row_off, dinv, n);

    // CSR fill: atomic-free single scatter
    fill_src<<<eb, 256, 0, stream>>>(src, dst, rank, row_off, e, ssrc);

    // layer 1: g1 = bf16(dinv * (x@W1)) ; a1 = relu(di*(g1[i]+sum g1[s]) + b1)
    gemm_xw<128, 64><<<(n + 63) / 64, 256, 0, stream>>>(x, W1, dinv, g1, n);
    aggregate64<true><<<(n + 3) / 4, 256, 0, stream>>>(g1, dinv, row_off, ssrc, b1, a1, n);

    // layer 2: g2 = bf16(dinv * (a1@W2)) ; out = di*(g2[i]+sum g2[s]) + b2
    gemm_xw<64, 40><<<(n + 63) / 64, 256, 0, stream>>>(a1, W2, dinv, g2, n);
    aggregate40<false><<<(n + 3) / 4, 256, 0, stream>>>(g2, dinv, row_off, ssrc, b2, (float*)d_out, n);
}